// Round 10
// baseline (206.039 us; speedup 1.0000x reference)
//
#include <hip/hip_runtime.h>
#include <hip/hip_bf16.h>
#include <math.h>

// Shapes (fixed by reference)
#define B_ 4
#define L_ 256
#define H_ 768
#define P_ 32896   // L*(L+1)/2
#define N_ 1536    // 2*H
#define K_ 768
#define M_ 1024    // B*L

typedef __attribute__((ext_vector_type(4))) float f32x4;
typedef __attribute__((ext_vector_type(8))) short s16x8;

__device__ __forceinline__ unsigned pack_bf16(float x, float y) {
    __hip_bfloat16 hx = __float2bfloat16(x);   // RTN
    __hip_bfloat16 hy = __float2bfloat16(y);
    const unsigned short ux = *(const unsigned short*)&hx;
    const unsigned short uy = *(const unsigned short*)&hy;
    return (unsigned)ux | ((unsigned)uy << 16);
}

// ---------------------------------------------------------------------------
// MFMA GEMM (unchanged from R4): T[m][n] = sum_k A[m][k]*Wsel[n][k]
// (+ bias for n < H). 64x64 tile, BK=64, 4 waves, XOR-swizzled LDS.
// ---------------------------------------------------------------------------
__global__ __launch_bounds__(256) void gemm_uv_mfma(
        const float* __restrict__ A, const float* __restrict__ W,
        const float* __restrict__ bias, float* __restrict__ T) {
    __shared__ __align__(16) char As[64 * 128];   // 64 rows x 64 bf16
    __shared__ __align__(16) char Bs[64 * 128];

    const int tid = threadIdx.x;
    const int bm = blockIdx.x * 64;
    const int bn = blockIdx.y * 64;
    const int lane = tid & 63;
    const int wave = tid >> 6;

    const int sr = tid >> 4;            // 0..15
    const int sk = (tid & 15) * 4;      // 0..60
    const float* wbase = (bn < H_) ? (W + (size_t)bn * N_)
                                   : (W + (size_t)(bn - H_) * N_ + H_);

    const int wm = (wave & 1) * 32;
    const int wn = (wave >> 1) * 32;
    const int l15 = lane & 15;
    const int l4  = lane >> 4;

    f32x4 acc[2][2] = {};

    for (int kt = 0; kt < K_; kt += 64) {
        __syncthreads();
#pragma unroll
        for (int ph = 0; ph < 4; ++ph) {
            const int row = ph * 16 + sr;
            const float4 av = *(const float4*)(A + (size_t)(bm + row) * K_ + kt + sk);
            const float4 bv = *(const float4*)(wbase + (size_t)row * N_ + kt + sk);
            const int chunk = sk >> 3;
            const int sub   = (sk & 4) ? 8 : 0;
            const int boff  = row * 128 + ((chunk ^ (row & 7)) * 16) + sub;
            *(uint2*)(As + boff) = make_uint2(pack_bf16(av.x, av.y), pack_bf16(av.z, av.w));
            *(uint2*)(Bs + boff) = make_uint2(pack_bf16(bv.x, bv.y), pack_bf16(bv.z, bv.w));
        }
        __syncthreads();
#pragma unroll
        for (int ks = 0; ks < 2; ++ks) {
            s16x8 af[2], bf[2];
#pragma unroll
            for (int mi = 0; mi < 2; ++mi) {
                const int row = wm + mi * 16 + l15;
                const int chunk = (ks * 4 + l4) ^ (row & 7);
                af[mi] = *(const s16x8*)(As + row * 128 + chunk * 16);
            }
#pragma unroll
            for (int ni = 0; ni < 2; ++ni) {
                const int row = wn + ni * 16 + l15;
                const int chunk = (ks * 4 + l4) ^ (row & 7);
                bf[ni] = *(const s16x8*)(Bs + row * 128 + chunk * 16);
            }
#pragma unroll
            for (int mi = 0; mi < 2; ++mi)
#pragma unroll
                for (int ni = 0; ni < 2; ++ni)
                    acc[mi][ni] = __builtin_amdgcn_mfma_f32_16x16x32_bf16(
                        af[mi], bf[ni], acc[mi][ni], 0, 0, 0);
        }
    }

#pragma unroll
    for (int mi = 0; mi < 2; ++mi)
#pragma unroll
        for (int ni = 0; ni < 2; ++ni) {
            const int gm0 = bm + wm + mi * 16 + l4 * 4;
            const int gn  = bn + wn + ni * 16 + l15;
            const float badd = (gn < H_) ? bias[gn] : 0.0f;
#pragma unroll
            for (int r = 0; r < 4; ++r)
                T[(size_t)(gm0 + r) * N_ + gn] = acc[mi][ni][r] + badd;
        }
}

// tanh(x) = 1 - 2/(exp2(2*log2e*x)+1); exact at +-inf. 5 VALU ops.
__device__ __forceinline__ float fast_tanh(float x) {
    const float e = __builtin_amdgcn_exp2f(x * 2.885390081777926815f);
    const float r = __builtin_amdgcn_rcpf(e + 1.0f);
    return fmaf(-2.0f, r, 1.0f);
}

__device__ __forceinline__ f32x4 tanh4(f32x4 u, f32x4 v) {
    f32x4 o;
    o.x = fast_tanh(u.x + v.x);
    o.y = fast_tanh(u.y + v.y);
    o.z = fast_tanh(u.z + v.z);
    o.w = fast_tanh(u.w + v.w);
    return o;
}

// ---------------------------------------------------------------------------
// Epilogue (byte-identical to R9). DIAGNOSTIC ROUND: launched TWICE below.
// Idempotent (reads stable T, rewrites identical values), so output is
// unchanged; total_dur = G + 2E, and E = total_dur - 123.3us (R9's G + E).
// ---------------------------------------------------------------------------
__global__ __launch_bounds__(192) void handshake_epilogue_seq(
        const float* __restrict__ T,
        float* __restrict__ out) {
    const int bid  = blockIdx.x;        // 0..1023
    const int b    = (bid & 7) >> 1;    // XCD-affine: xcd = bid%8 = 2b+half
    const int half = bid & 1;
    const int i1   = bid >> 3;          // 0..127
    const int i2   = 255 - i1;          // partner row, i2 > i1 always

    // j-range split balancing write count (257 total):
    const int j_mid = (i1 <= 63) ? (i1 + 128) : 191;
    const int jlo = half ? j_mid : i1;
    const int jhi = half ? 256 : j_mid;

    const int h = threadIdx.x * 4;      // 192 threads * 4 = 768 floats/row
    const float* Tb = T + (size_t)b * L_ * N_;
    const float* Vb = Tb + H_ + h;      // V row j at Vb + j*N_

    const f32x4 u1 = *(const f32x4*)(Tb + (size_t)i1 * N_ + h);
    const f32x4 u2 = *(const f32x4*)(Tb + (size_t)i2 * N_ + h);

    const size_t off1 = (size_t)i1 * (2 * L_ + 1 - i1) / 2;
    const size_t off2 = (size_t)i2 * (2 * L_ + 1 - i2) / 2;
    // o1 writes every j in [jlo, jhi): position off1 + (j - i1).
    float* o1 = out + ((size_t)b * P_ + off1 + (size_t)(jlo - i1)) * H_ + h;
    // o2 writes only j >= i2; first write at j = max(jlo, i2).
    const int j2first = (jlo > i2) ? jlo : i2;
    float* o2 = out + ((size_t)b * P_ + off2 + (size_t)(j2first - i2)) * H_ + h;

    // Depth-2 V prefetch (named regs, no runtime-indexed arrays).
    f32x4 v0 = *(const f32x4*)(Vb + (size_t)jlo * N_);
    f32x4 v1 = (jlo + 1 < 256) ? *(const f32x4*)(Vb + (size_t)(jlo + 1) * N_) : v0;

    for (int j = jlo; j < jhi; ++j) {
        const f32x4 vc = v0;
        v0 = v1;
        if (j + 2 < 256)                 // uniform branch
            v1 = *(const f32x4*)(Vb + (size_t)(j + 2) * N_);

        __builtin_nontemporal_store(tanh4(u1, vc), (f32x4*)o1);
        o1 += H_;
        if (j >= i2) {                   // uniform branch
            __builtin_nontemporal_store(tanh4(u2, vc), (f32x4*)o2);
            o2 += H_;
        }
    }
}

extern "C" void kernel_launch(void* const* d_in, const int* in_sizes, int n_in,
                              void* d_out, int out_size, void* d_ws, size_t ws_size,
                              hipStream_t stream) {
    const float* seq  = (const float*)d_in[0];   // (B, L, H) fp32
    const float* W    = (const float*)d_in[1];   // (H, 2H) fp32
    const float* bias = (const float*)d_in[2];   // (H,) fp32
    float* out = (float*)d_out;                  // (B, P, H) fp32
    float* T   = (float*)d_ws;                   // (B*L, 2H) fp32 = 6.3 MB

    dim3 g1(M_ / 64, N_ / 64);                   // 16 x 24 = 384 blocks
    gemm_uv_mfma<<<g1, 256, 0, stream>>>(seq, W, bias, T);

    // DIAGNOSTIC: epilogue launched twice (idempotent). E = dur - 123.3us.
    handshake_epilogue_seq<<<1024, 192, 0, stream>>>(T, out);
    handshake_epilogue_seq<<<1024, 192, 0, stream>>>(T, out);
}

// Round 11
// 104.701 us; speedup vs baseline: 1.9679x; 1.9679x over previous
//
#include <hip/hip_runtime.h>
#include <hip/hip_bf16.h>
#include <math.h>

// Shapes (fixed by reference)
#define B_ 4
#define L_ 256
#define H_ 768
#define P_ 32896   // L*(L+1)/2
#define N_ 1536    // 2*H
#define K_ 768
#define M_ 1024    // B*L

typedef __attribute__((ext_vector_type(4))) float f32x4;
typedef __attribute__((ext_vector_type(8))) short s16x8;
typedef const __attribute__((address_space(1))) void* gptr_t;
typedef __attribute__((address_space(3))) void* sptr_t;

__device__ __forceinline__ unsigned pack_bf16(float x, float y) {
    __hip_bfloat16 hx = __float2bfloat16(x);   // RTN
    __hip_bfloat16 hy = __float2bfloat16(y);
    const unsigned short ux = *(const unsigned short*)&hx;
    const unsigned short uy = *(const unsigned short*)&hy;
    return (unsigned)ux | ((unsigned)uy << 16);
}

// ---------------------------------------------------------------------------
// Stage 0: fp32 -> bf16 conversion (memory-bound, ~11 MB, ~2 us).
//   Abf[m][k] = bf16(A[m][k])                          (1024 x 768)
//   Wbf[n][k] = bf16(Wsel[n][k])  n<768: W[n][k]; n>=768: W[n-768][768+k]
// One linear pass over each input; coalesced float4 reads, 8B writes.
// ---------------------------------------------------------------------------
__global__ __launch_bounds__(256) void convert_to_bf16(
        const float* __restrict__ A, const float* __restrict__ W,
        unsigned short* __restrict__ Abf, unsigned short* __restrict__ Wbf) {
    const int idx = blockIdx.x * 256 + threadIdx.x;   // float4 index
    const int nA4 = (M_ * K_) / 4;                    // 196608
    const int nW4 = (H_ * N_) / 4;                    // 294912
    if (idx < nA4) {
        const float4 v = ((const float4*)A)[idx];
        ((uint2*)Abf)[idx] = make_uint2(pack_bf16(v.x, v.y), pack_bf16(v.z, v.w));
    } else if (idx < nA4 + nW4) {
        const int wi = idx - nA4;
        const int h  = wi / 384;          // 384 float4 per W row
        const int c  = (wi % 384) * 4;
        const float4 v = ((const float4*)W)[wi];
        const int n = h + ((c >= 768) ? 768 : 0);
        const int k = (c >= 768) ? (c - 768) : c;
        *(uint2*)(Wbf + (size_t)n * K_ + k) =
            make_uint2(pack_bf16(v.x, v.y), pack_bf16(v.z, v.w));
    }
}

// ---------------------------------------------------------------------------
// Stage 1: bf16 MFMA GEMM with global_load_lds DMA staging (no VALU packing).
// T[m][n] = sum_k Abf[m][k]*Wbf[n][k] (+ bias for n < H). 64x64 tile, BK=64,
// 4 waves in 2x2 of 32x32. LDS XOR-swizzle achieved by PRE-SWIZZLING the
// per-lane GLOBAL source chunk (LDS dest of global_load_lds is linear:
// wave-uniform base + lane*16). LDS[r][c] = src[r][c ^ (r&7)]; readers XOR
// back -> ds_read_b128 conflict-free (8 distinct banks-groups per 8 rows).
// ---------------------------------------------------------------------------
__global__ __launch_bounds__(256) void gemm_uv_bf16(
        const unsigned short* __restrict__ Abf,
        const unsigned short* __restrict__ Wbf,
        const float* __restrict__ bias, float* __restrict__ T) {
    __shared__ __align__(16) char As[64 * 128];   // 64 rows x 64 bf16
    __shared__ __align__(16) char Bs[64 * 128];

    const int tid  = threadIdx.x;
    const int bm   = blockIdx.x * 64;
    const int bn   = blockIdx.y * 64;
    const int lane = tid & 63;
    const int wave = tid >> 6;

    const int wm  = (wave & 1) * 32;
    const int wn  = (wave >> 1) * 32;
    const int l15 = lane & 15;
    const int l4  = lane >> 4;

    // Staging geometry: wave w stages rows [w*16, w*16+16) of both tiles,
    // as 2 issues of 8 rows (64 lanes x 16B = 1KB per issue).
    const int rl = lane >> 3;            // row within 8-row issue
    const int cc = lane & 7;             // 16B chunk within row

    f32x4 acc[2][2] = {};

    for (int kt = 0; kt < K_; kt += 64) {
        __syncthreads();                 // LDS reuse guard (drains vmcnt)
#pragma unroll
        for (int is = 0; is < 2; ++is) {
            const int r  = wave * 16 + is * 8 + rl;
            const int cp = cc ^ (r & 7);              // pre-swizzled source
            __builtin_amdgcn_global_load_lds(
                (gptr_t)(Abf + (size_t)(bm + r) * K_ + kt + cp * 8),
                (sptr_t)(As + (wave * 16 + is * 8) * 128), 16, 0, 0);
            __builtin_amdgcn_global_load_lds(
                (gptr_t)(Wbf + (size_t)(bn + r) * K_ + kt + cp * 8),
                (sptr_t)(Bs + (wave * 16 + is * 8) * 128), 16, 0, 0);
        }
        __syncthreads();                 // staging complete
#pragma unroll
        for (int ks = 0; ks < 2; ++ks) {
            s16x8 af[2], bf[2];
#pragma unroll
            for (int mi = 0; mi < 2; ++mi) {
                const int row = wm + mi * 16 + l15;
                const int chunk = (ks * 4 + l4) ^ (row & 7);
                af[mi] = *(const s16x8*)(As + row * 128 + chunk * 16);
            }
#pragma unroll
            for (int ni = 0; ni < 2; ++ni) {
                const int row = wn + ni * 16 + l15;
                const int chunk = (ks * 4 + l4) ^ (row & 7);
                bf[ni] = *(const s16x8*)(Bs + row * 128 + chunk * 16);
            }
#pragma unroll
            for (int mi = 0; mi < 2; ++mi)
#pragma unroll
                for (int ni = 0; ni < 2; ++ni)
                    acc[mi][ni] = __builtin_amdgcn_mfma_f32_16x16x32_bf16(
                        af[mi], bf[ni], acc[mi][ni], 0, 0, 0);
        }
    }

    // C-write (fp32), bias folded into U half. D: col=lane&15, row=(lane>>4)*4+r.
#pragma unroll
    for (int mi = 0; mi < 2; ++mi)
#pragma unroll
        for (int ni = 0; ni < 2; ++ni) {
            const int gm0 = bm + wm + mi * 16 + l4 * 4;
            const int gn  = bn + wn + ni * 16 + l15;
            const float badd = (gn < H_) ? bias[gn] : 0.0f;
#pragma unroll
            for (int r = 0; r < 4; ++r)
                T[(size_t)(gm0 + r) * N_ + gn] = acc[mi][ni][r] + badd;
        }
}

// ---------------------------------------------------------------------------
// Fallback GEMM (R4): fp32 inputs, VALU pack staging. Used only if ws_size
// is too small for the bf16 scratch copies.
// ---------------------------------------------------------------------------
__global__ __launch_bounds__(256) void gemm_uv_mfma(
        const float* __restrict__ A, const float* __restrict__ W,
        const float* __restrict__ bias, float* __restrict__ T) {
    __shared__ __align__(16) char As[64 * 128];
    __shared__ __align__(16) char Bs[64 * 128];

    const int tid = threadIdx.x;
    const int bm = blockIdx.x * 64;
    const int bn = blockIdx.y * 64;
    const int lane = tid & 63;
    const int wave = tid >> 6;

    const int sr = tid >> 4;
    const int sk = (tid & 15) * 4;
    const float* wbase = (bn < H_) ? (W + (size_t)bn * N_)
                                   : (W + (size_t)(bn - H_) * N_ + H_);

    const int wm = (wave & 1) * 32;
    const int wn = (wave >> 1) * 32;
    const int l15 = lane & 15;
    const int l4  = lane >> 4;

    f32x4 acc[2][2] = {};

    for (int kt = 0; kt < K_; kt += 64) {
        __syncthreads();
#pragma unroll
        for (int ph = 0; ph < 4; ++ph) {
            const int row = ph * 16 + sr;
            const float4 av = *(const float4*)(A + (size_t)(bm + row) * K_ + kt + sk);
            const float4 bv = *(const float4*)(wbase + (size_t)row * N_ + kt + sk);
            const int chunk = sk >> 3;
            const int sub   = (sk & 4) ? 8 : 0;
            const int boff  = row * 128 + ((chunk ^ (row & 7)) * 16) + sub;
            *(uint2*)(As + boff) = make_uint2(pack_bf16(av.x, av.y), pack_bf16(av.z, av.w));
            *(uint2*)(Bs + boff) = make_uint2(pack_bf16(bv.x, bv.y), pack_bf16(bv.z, bv.w));
        }
        __syncthreads();
#pragma unroll
        for (int ks = 0; ks < 2; ++ks) {
            s16x8 af[2], bf[2];
#pragma unroll
            for (int mi = 0; mi < 2; ++mi) {
                const int row = wm + mi * 16 + l15;
                const int chunk = (ks * 4 + l4) ^ (row & 7);
                af[mi] = *(const s16x8*)(As + row * 128 + chunk * 16);
            }
#pragma unroll
            for (int ni = 0; ni < 2; ++ni) {
                const int row = wn + ni * 16 + l15;
                const int chunk = (ks * 4 + l4) ^ (row & 7);
                bf[ni] = *(const s16x8*)(Bs + row * 128 + chunk * 16);
            }
#pragma unroll
            for (int mi = 0; mi < 2; ++mi)
#pragma unroll
                for (int ni = 0; ni < 2; ++ni)
                    acc[mi][ni] = __builtin_amdgcn_mfma_f32_16x16x32_bf16(
                        af[mi], bf[ni], acc[mi][ni], 0, 0, 0);
        }
    }

#pragma unroll
    for (int mi = 0; mi < 2; ++mi)
#pragma unroll
        for (int ni = 0; ni < 2; ++ni) {
            const int gm0 = bm + wm + mi * 16 + l4 * 4;
            const int gn  = bn + wn + ni * 16 + l15;
            const float badd = (gn < H_) ? bias[gn] : 0.0f;
#pragma unroll
            for (int r = 0; r < 4; ++r)
                T[(size_t)(gm0 + r) * N_ + gn] = acc[mi][ni][r] + badd;
        }
}

// tanh(x) = 1 - 2/(exp2(2*log2e*x)+1); exact at +-inf. 5 VALU ops.
__device__ __forceinline__ float fast_tanh(float x) {
    const float e = __builtin_amdgcn_exp2f(x * 2.885390081777926815f);
    const float r = __builtin_amdgcn_rcpf(e + 1.0f);
    return fmaf(-2.0f, r, 1.0f);
}

__device__ __forceinline__ f32x4 tanh4(f32x4 u, f32x4 v) {
    f32x4 o;
    o.x = fast_tanh(u.x + v.x);
    o.y = fast_tanh(u.y + v.y);
    o.z = fast_tanh(u.z + v.z);
    o.w = fast_tanh(u.w + v.w);
    return o;
}

// ---------------------------------------------------------------------------
// Epilogue (byte-identical to R9): sequential-write pair structure +
// XCD-affinity swizzle + NT stores. Measured at ~83 us (R10 double-launch).
// ---------------------------------------------------------------------------
__global__ __launch_bounds__(192) void handshake_epilogue_seq(
        const float* __restrict__ T,
        float* __restrict__ out) {
    const int bid  = blockIdx.x;        // 0..1023
    const int b    = (bid & 7) >> 1;    // XCD-affine: xcd = bid%8 = 2b+half
    const int half = bid & 1;
    const int i1   = bid >> 3;          // 0..127
    const int i2   = 255 - i1;

    const int j_mid = (i1 <= 63) ? (i1 + 128) : 191;
    const int jlo = half ? j_mid : i1;
    const int jhi = half ? 256 : j_mid;

    const int h = threadIdx.x * 4;
    const float* Tb = T + (size_t)b * L_ * N_;
    const float* Vb = Tb + H_ + h;

    const f32x4 u1 = *(const f32x4*)(Tb + (size_t)i1 * N_ + h);
    const f32x4 u2 = *(const f32x4*)(Tb + (size_t)i2 * N_ + h);

    const size_t off1 = (size_t)i1 * (2 * L_ + 1 - i1) / 2;
    const size_t off2 = (size_t)i2 * (2 * L_ + 1 - i2) / 2;
    float* o1 = out + ((size_t)b * P_ + off1 + (size_t)(jlo - i1)) * H_ + h;
    const int j2first = (jlo > i2) ? jlo : i2;
    float* o2 = out + ((size_t)b * P_ + off2 + (size_t)(j2first - i2)) * H_ + h;

    f32x4 v0 = *(const f32x4*)(Vb + (size_t)jlo * N_);
    f32x4 v1 = (jlo + 1 < 256) ? *(const f32x4*)(Vb + (size_t)(jlo + 1) * N_) : v0;

    for (int j = jlo; j < jhi; ++j) {
        const f32x4 vc = v0;
        v0 = v1;
        if (j + 2 < 256)
            v1 = *(const f32x4*)(Vb + (size_t)(j + 2) * N_);

        __builtin_nontemporal_store(tanh4(u1, vc), (f32x4*)o1);
        o1 += H_;
        if (j >= i2) {
            __builtin_nontemporal_store(tanh4(u2, vc), (f32x4*)o2);
            o2 += H_;
        }
    }
}

extern "C" void kernel_launch(void* const* d_in, const int* in_sizes, int n_in,
                              void* d_out, int out_size, void* d_ws, size_t ws_size,
                              hipStream_t stream) {
    const float* seq  = (const float*)d_in[0];   // (B, L, H) fp32
    const float* W    = (const float*)d_in[1];   // (H, 2H) fp32
    const float* bias = (const float*)d_in[2];   // (H,) fp32
    float* out = (float*)d_out;                  // (B, P, H) fp32

    char* ws = (char*)d_ws;
    float* T = (float*)ws;                               // 6.29 MB
    const size_t T_BYTES = (size_t)M_ * N_ * 4;
    unsigned short* Abf = (unsigned short*)(ws + T_BYTES);               // 1.57 MB
    unsigned short* Wbf = (unsigned short*)(ws + T_BYTES + (size_t)M_ * K_ * 2); // 2.36 MB
    const size_t NEED = T_BYTES + (size_t)M_ * K_ * 2 + (size_t)K_ * N_ * 2;

    dim3 g1(M_ / 64, N_ / 64);                   // 16 x 24 = 384 blocks
    if (ws_size >= NEED) {
        convert_to_bf16<<<1920, 256, 0, stream>>>(seq, W, Abf, Wbf);
        gemm_uv_bf16<<<g1, 256, 0, stream>>>(Abf, Wbf, bias, T);
    } else {
        gemm_uv_mfma<<<g1, 256, 0, stream>>>(seq, W, bias, T);
    }

    handshake_epilogue_seq<<<1024, 192, 0, stream>>>(T, out);
}

// Round 12
// 103.874 us; speedup vs baseline: 1.9835x; 1.0080x over previous
//
#include <hip/hip_runtime.h>
#include <hip/hip_bf16.h>
#include <math.h>

// Shapes (fixed by reference)
#define B_ 4
#define L_ 256
#define H_ 768
#define P_ 32896   // L*(L+1)/2
#define N_ 1536    // 2*H
#define K_ 768
#define M_ 1024    // B*L

typedef __attribute__((ext_vector_type(4))) float f32x4;
typedef __attribute__((ext_vector_type(8))) short s16x8;
typedef const __attribute__((address_space(1))) void* gptr_t;
typedef __attribute__((address_space(3))) void* sptr_t;

__device__ __forceinline__ unsigned pack_bf16(float x, float y) {
    __hip_bfloat16 hx = __float2bfloat16(x);   // RTN
    __hip_bfloat16 hy = __float2bfloat16(y);
    const unsigned short ux = *(const unsigned short*)&hx;
    const unsigned short uy = *(const unsigned short*)&hy;
    return (unsigned)ux | ((unsigned)uy << 16);
}

// ---------------------------------------------------------------------------
// Stage 0: fp32 -> bf16 conversion (memory-bound, ~24 MB traffic).
// ---------------------------------------------------------------------------
__global__ __launch_bounds__(256) void convert_to_bf16(
        const float* __restrict__ A, const float* __restrict__ W,
        unsigned short* __restrict__ Abf, unsigned short* __restrict__ Wbf) {
    const int idx = blockIdx.x * 256 + threadIdx.x;   // float4 index
    const int nA4 = (M_ * K_) / 4;                    // 196608
    const int nW4 = (H_ * N_) / 4;                    // 294912
    if (idx < nA4) {
        const float4 v = ((const float4*)A)[idx];
        ((uint2*)Abf)[idx] = make_uint2(pack_bf16(v.x, v.y), pack_bf16(v.z, v.w));
    } else if (idx < nA4 + nW4) {
        const int wi = idx - nA4;
        const int h  = wi / 384;          // 384 float4 per W row
        const int c  = (wi % 384) * 4;
        const float4 v = ((const float4*)W)[wi];
        const int n = h + ((c >= 768) ? 768 : 0);
        const int k = (c >= 768) ? (c - 768) : c;
        *(uint2*)(Wbf + (size_t)n * K_ + k) =
            make_uint2(pack_bf16(v.x, v.y), pack_bf16(v.z, v.w));
    }
}

// ---------------------------------------------------------------------------
// Stage 1: bf16 MFMA GEMM with global_load_lds DMA staging (unchanged R11).
// ---------------------------------------------------------------------------
__global__ __launch_bounds__(256) void gemm_uv_bf16(
        const unsigned short* __restrict__ Abf,
        const unsigned short* __restrict__ Wbf,
        const float* __restrict__ bias, float* __restrict__ T) {
    __shared__ __align__(16) char As[64 * 128];   // 64 rows x 64 bf16
    __shared__ __align__(16) char Bs[64 * 128];

    const int tid  = threadIdx.x;
    const int bm   = blockIdx.x * 64;
    const int bn   = blockIdx.y * 64;
    const int lane = tid & 63;
    const int wave = tid >> 6;

    const int wm  = (wave & 1) * 32;
    const int wn  = (wave >> 1) * 32;
    const int l15 = lane & 15;
    const int l4  = lane >> 4;

    const int rl = lane >> 3;            // row within 8-row issue
    const int cc = lane & 7;             // 16B chunk within row

    f32x4 acc[2][2] = {};

    for (int kt = 0; kt < K_; kt += 64) {
        __syncthreads();
#pragma unroll
        for (int is = 0; is < 2; ++is) {
            const int r  = wave * 16 + is * 8 + rl;
            const int cp = cc ^ (r & 7);              // pre-swizzled source
            __builtin_amdgcn_global_load_lds(
                (gptr_t)(Abf + (size_t)(bm + r) * K_ + kt + cp * 8),
                (sptr_t)(As + (wave * 16 + is * 8) * 128), 16, 0, 0);
            __builtin_amdgcn_global_load_lds(
                (gptr_t)(Wbf + (size_t)(bn + r) * K_ + kt + cp * 8),
                (sptr_t)(Bs + (wave * 16 + is * 8) * 128), 16, 0, 0);
        }
        __syncthreads();
#pragma unroll
        for (int ks = 0; ks < 2; ++ks) {
            s16x8 af[2], bf[2];
#pragma unroll
            for (int mi = 0; mi < 2; ++mi) {
                const int row = wm + mi * 16 + l15;
                const int chunk = (ks * 4 + l4) ^ (row & 7);
                af[mi] = *(const s16x8*)(As + row * 128 + chunk * 16);
            }
#pragma unroll
            for (int ni = 0; ni < 2; ++ni) {
                const int row = wn + ni * 16 + l15;
                const int chunk = (ks * 4 + l4) ^ (row & 7);
                bf[ni] = *(const s16x8*)(Bs + row * 128 + chunk * 16);
            }
#pragma unroll
            for (int mi = 0; mi < 2; ++mi)
#pragma unroll
                for (int ni = 0; ni < 2; ++ni)
                    acc[mi][ni] = __builtin_amdgcn_mfma_f32_16x16x32_bf16(
                        af[mi], bf[ni], acc[mi][ni], 0, 0, 0);
        }
    }

#pragma unroll
    for (int mi = 0; mi < 2; ++mi)
#pragma unroll
        for (int ni = 0; ni < 2; ++ni) {
            const int gm0 = bm + wm + mi * 16 + l4 * 4;
            const int gn  = bn + wn + ni * 16 + l15;
            const float badd = (gn < H_) ? bias[gn] : 0.0f;
#pragma unroll
            for (int r = 0; r < 4; ++r)
                T[(size_t)(gm0 + r) * N_ + gn] = acc[mi][ni][r] + badd;
        }
}

// ---------------------------------------------------------------------------
// Fallback GEMM (R4-style, fp32 inputs) if ws too small for bf16 scratch.
// ---------------------------------------------------------------------------
__global__ __launch_bounds__(256) void gemm_uv_mfma(
        const float* __restrict__ A, const float* __restrict__ W,
        const float* __restrict__ bias, float* __restrict__ T) {
    __shared__ __align__(16) char As[64 * 128];
    __shared__ __align__(16) char Bs[64 * 128];

    const int tid = threadIdx.x;
    const int bm = blockIdx.x * 64;
    const int bn = blockIdx.y * 64;
    const int lane = tid & 63;
    const int wave = tid >> 6;

    const int sr = tid >> 4;
    const int sk = (tid & 15) * 4;
    const float* wbase = (bn < H_) ? (W + (size_t)bn * N_)
                                   : (W + (size_t)(bn - H_) * N_ + H_);

    const int wm = (wave & 1) * 32;
    const int wn = (wave >> 1) * 32;
    const int l15 = lane & 15;
    const int l4  = lane >> 4;

    f32x4 acc[2][2] = {};

    for (int kt = 0; kt < K_; kt += 64) {
        __syncthreads();
#pragma unroll
        for (int ph = 0; ph < 4; ++ph) {
            const int row = ph * 16 + sr;
            const float4 av = *(const float4*)(A + (size_t)(bm + row) * K_ + kt + sk);
            const float4 bv = *(const float4*)(wbase + (size_t)row * N_ + kt + sk);
            const int chunk = sk >> 3;
            const int sub   = (sk & 4) ? 8 : 0;
            const int boff  = row * 128 + ((chunk ^ (row & 7)) * 16) + sub;
            *(uint2*)(As + boff) = make_uint2(pack_bf16(av.x, av.y), pack_bf16(av.z, av.w));
            *(uint2*)(Bs + boff) = make_uint2(pack_bf16(bv.x, bv.y), pack_bf16(bv.z, bv.w));
        }
        __syncthreads();
#pragma unroll
        for (int ks = 0; ks < 2; ++ks) {
            s16x8 af[2], bf[2];
#pragma unroll
            for (int mi = 0; mi < 2; ++mi) {
                const int row = wm + mi * 16 + l15;
                const int chunk = (ks * 4 + l4) ^ (row & 7);
                af[mi] = *(const s16x8*)(As + row * 128 + chunk * 16);
            }
#pragma unroll
            for (int ni = 0; ni < 2; ++ni) {
                const int row = wn + ni * 16 + l15;
                const int chunk = (ks * 4 + l4) ^ (row & 7);
                bf[ni] = *(const s16x8*)(Bs + row * 128 + chunk * 16);
            }
#pragma unroll
            for (int mi = 0; mi < 2; ++mi)
#pragma unroll
                for (int ni = 0; ni < 2; ++ni)
                    acc[mi][ni] = __builtin_amdgcn_mfma_f32_16x16x32_bf16(
                        af[mi], bf[ni], acc[mi][ni], 0, 0, 0);
        }
    }

#pragma unroll
    for (int mi = 0; mi < 2; ++mi)
#pragma unroll
        for (int ni = 0; ni < 2; ++ni) {
            const int gm0 = bm + wm + mi * 16 + l4 * 4;
            const int gn  = bn + wn + ni * 16 + l15;
            const float badd = (gn < H_) ? bias[gn] : 0.0f;
#pragma unroll
            for (int r = 0; r < 4; ++r)
                T[(size_t)(gm0 + r) * N_ + gn] = acc[mi][ni][r] + badd;
        }
}

// tanh(x) = 1 - 2/(exp2(2*log2e*x)+1); exact at +-inf. 5 VALU ops.
__device__ __forceinline__ float fast_tanh(float x) {
    const float e = __builtin_amdgcn_exp2f(x * 2.885390081777926815f);
    const float r = __builtin_amdgcn_rcpf(e + 1.0f);
    return fmaf(-2.0f, r, 1.0f);
}

__device__ __forceinline__ f32x4 tanh4(f32x4 u, f32x4 v) {
    f32x4 o;
    o.x = fast_tanh(u.x + v.x);
    o.y = fast_tanh(u.y + v.y);
    o.z = fast_tanh(u.z + v.z);
    o.w = fast_tanh(u.w + v.w);
    return o;
}

// ---------------------------------------------------------------------------
// Epilogue v2: TWO adjacent pairs per block -> 4 sequential output streams
// share one j-sweep, halving V-read traffic (400 -> ~200 MB) with the write
// pattern unchanged (same NT stores, same 384KB-contiguous streams).
// Block (it, b, half): rows iA=2it, iB=2it+1, iC=254-2it, iD=255-2it
// (iA<iB<iC<iD); j-half split at jm = pair-A median (pair-B medians differ
// by <=1, balance verified +-3 rows of 257). Stream s writes j in
// [max(jlo,s), jhi) at out position off(s)+j-s; pointer advances only on
// j>=s iterations (R6 lesson). xcd = bid&7 = 2b+half keeps batch b's V on
// XCDs {2b,2b+1}.
// ---------------------------------------------------------------------------
__global__ __launch_bounds__(192) void handshake_epilogue_seq2(
        const float* __restrict__ T,
        float* __restrict__ out) {
    const int bid  = blockIdx.x;        // 0..511
    const int half = bid & 1;
    const int b    = (bid >> 1) & 3;
    const int it   = bid >> 3;          // 0..63

    const int iA = 2 * it, iB = 2 * it + 1;
    const int iC = 254 - 2 * it, iD = 255 - 2 * it;

    const int jm  = (iA <= 63) ? (iA + 128) : 191;
    const int jlo = half ? jm : iA;
    const int jhi = half ? 256 : jm;

    const int h = threadIdx.x * 4;      // 192 threads * 4 = 768 floats/row
    const float* Tb = T + (size_t)b * L_ * N_;
    const float* Vb = Tb + H_ + h;

    const f32x4 uA = *(const f32x4*)(Tb + (size_t)iA * N_ + h);
    const f32x4 uB = *(const f32x4*)(Tb + (size_t)iB * N_ + h);
    const f32x4 uC = *(const f32x4*)(Tb + (size_t)iC * N_ + h);
    const f32x4 uD = *(const f32x4*)(Tb + (size_t)iD * N_ + h);

    const size_t obase = (size_t)b * P_;
    // off(i) = i*(2L+1-i)/2 ; stream start = max(jlo, i)
#define MK_PTR(i)                                                         \
    (out + (obase + (size_t)(i) * (2 * L_ + 1 - (i)) / 2 +               \
            (size_t)(((jlo > (i)) ? jlo : (i)) - (i))) * H_ + h)
    float* oA = MK_PTR(iA);
    float* oB = MK_PTR(iB);
    float* oC = MK_PTR(iC);
    float* oD = MK_PTR(iD);
#undef MK_PTR

    // Depth-2 V prefetch (named regs).
    f32x4 v0 = *(const f32x4*)(Vb + (size_t)jlo * N_);
    f32x4 v1 = (jlo + 1 < 256) ? *(const f32x4*)(Vb + (size_t)(jlo + 1) * N_) : v0;

    for (int j = jlo; j < jhi; ++j) {
        const f32x4 vc = v0;
        v0 = v1;
        if (j + 2 < 256)                 // uniform branch
            v1 = *(const f32x4*)(Vb + (size_t)(j + 2) * N_);

        // jlo >= iA always -> stream A unconditional.
        __builtin_nontemporal_store(tanh4(uA, vc), (f32x4*)oA);
        oA += H_;
        if (j >= iB) {                   // uniform
            __builtin_nontemporal_store(tanh4(uB, vc), (f32x4*)oB);
            oB += H_;
        }
        if (j >= iC) {                   // uniform
            __builtin_nontemporal_store(tanh4(uC, vc), (f32x4*)oC);
            oC += H_;
        }
        if (j >= iD) {                   // uniform
            __builtin_nontemporal_store(tanh4(uD, vc), (f32x4*)oD);
            oD += H_;
        }
    }
}

extern "C" void kernel_launch(void* const* d_in, const int* in_sizes, int n_in,
                              void* d_out, int out_size, void* d_ws, size_t ws_size,
                              hipStream_t stream) {
    const float* seq  = (const float*)d_in[0];   // (B, L, H) fp32
    const float* W    = (const float*)d_in[1];   // (H, 2H) fp32
    const float* bias = (const float*)d_in[2];   // (H,) fp32
    float* out = (float*)d_out;                  // (B, P, H) fp32

    char* ws = (char*)d_ws;
    float* T = (float*)ws;                               // 6.29 MB
    const size_t T_BYTES = (size_t)M_ * N_ * 4;
    unsigned short* Abf = (unsigned short*)(ws + T_BYTES);               // 1.57 MB
    unsigned short* Wbf = (unsigned short*)(ws + T_BYTES + (size_t)M_ * K_ * 2); // 2.36 MB
    const size_t NEED = T_BYTES + (size_t)M_ * K_ * 2 + (size_t)K_ * N_ * 2;

    dim3 g1(M_ / 64, N_ / 64);                   // 16 x 24 = 384 blocks
    if (ws_size >= NEED) {
        convert_to_bf16<<<1920, 256, 0, stream>>>(seq, W, Abf, Wbf);
        gemm_uv_bf16<<<g1, 256, 0, stream>>>(Abf, Wbf, bias, T);
    } else {
        gemm_uv_mfma<<<g1, 256, 0, stream>>>(seq, W, bias, T);
    }

    handshake_epilogue_seq2<<<512, 192, 0, stream>>>(T, out);
}

// Round 13
// 94.505 us; speedup vs baseline: 2.1802x; 1.0991x over previous
//
#include <hip/hip_runtime.h>
#include <hip/hip_bf16.h>
#include <math.h>

// Shapes (fixed by reference)
#define B_ 4
#define L_ 256
#define H_ 768
#define P_ 32896   // L*(L+1)/2
#define N_ 1536    // 2*H
#define K_ 768
#define M_ 1024    // B*L

typedef __attribute__((ext_vector_type(4))) float f32x4;
typedef __attribute__((ext_vector_type(8))) short s16x8;
typedef const __attribute__((address_space(1))) void* gptr_t;
typedef __attribute__((address_space(3))) void* sptr_t;

__device__ __forceinline__ unsigned pack_bf16(float x, float y) {
    __hip_bfloat16 hx = __float2bfloat16(x);   // RTN
    __hip_bfloat16 hy = __float2bfloat16(y);
    const unsigned short ux = *(const unsigned short*)&hx;
    const unsigned short uy = *(const unsigned short*)&hy;
    return (unsigned)ux | ((unsigned)uy << 16);
}

// ---------------------------------------------------------------------------
// Stage 0: fp32 -> bf16 conversion (memory-bound, ~24 MB traffic).
// ---------------------------------------------------------------------------
__global__ __launch_bounds__(256) void convert_to_bf16(
        const float* __restrict__ A, const float* __restrict__ W,
        unsigned short* __restrict__ Abf, unsigned short* __restrict__ Wbf) {
    const int idx = blockIdx.x * 256 + threadIdx.x;   // float4 index
    const int nA4 = (M_ * K_) / 4;                    // 196608
    const int nW4 = (H_ * N_) / 4;                    // 294912
    if (idx < nA4) {
        const float4 v = ((const float4*)A)[idx];
        ((uint2*)Abf)[idx] = make_uint2(pack_bf16(v.x, v.y), pack_bf16(v.z, v.w));
    } else if (idx < nA4 + nW4) {
        const int wi = idx - nA4;
        const int h  = wi / 384;          // 384 float4 per W row
        const int c  = (wi % 384) * 4;
        const float4 v = ((const float4*)W)[wi];
        const int n = h + ((c >= 768) ? 768 : 0);
        const int k = (c >= 768) ? (c - 768) : c;
        *(uint2*)(Wbf + (size_t)n * K_ + k) =
            make_uint2(pack_bf16(v.x, v.y), pack_bf16(v.z, v.w));
    }
}

// ---------------------------------------------------------------------------
// Stage 1: bf16 MFMA GEMM with global_load_lds DMA staging (unchanged R11).
// T[m][n] = sum_k Abf[m][k]*Wbf[n][k] (+ bias for n < H).
// ---------------------------------------------------------------------------
__global__ __launch_bounds__(256) void gemm_uv_bf16(
        const unsigned short* __restrict__ Abf,
        const unsigned short* __restrict__ Wbf,
        const float* __restrict__ bias, float* __restrict__ T) {
    __shared__ __align__(16) char As[64 * 128];   // 64 rows x 64 bf16
    __shared__ __align__(16) char Bs[64 * 128];

    const int tid  = threadIdx.x;
    const int bm   = blockIdx.x * 64;
    const int bn   = blockIdx.y * 64;
    const int lane = tid & 63;
    const int wave = tid >> 6;

    const int wm  = (wave & 1) * 32;
    const int wn  = (wave >> 1) * 32;
    const int l15 = lane & 15;
    const int l4  = lane >> 4;

    const int rl = lane >> 3;            // row within 8-row issue
    const int cc = lane & 7;             // 16B chunk within row

    f32x4 acc[2][2] = {};

    for (int kt = 0; kt < K_; kt += 64) {
        __syncthreads();
#pragma unroll
        for (int is = 0; is < 2; ++is) {
            const int r  = wave * 16 + is * 8 + rl;
            const int cp = cc ^ (r & 7);              // pre-swizzled source
            __builtin_amdgcn_global_load_lds(
                (gptr_t)(Abf + (size_t)(bm + r) * K_ + kt + cp * 8),
                (sptr_t)(As + (wave * 16 + is * 8) * 128), 16, 0, 0);
            __builtin_amdgcn_global_load_lds(
                (gptr_t)(Wbf + (size_t)(bn + r) * K_ + kt + cp * 8),
                (sptr_t)(Bs + (wave * 16 + is * 8) * 128), 16, 0, 0);
        }
        __syncthreads();
#pragma unroll
        for (int ks = 0; ks < 2; ++ks) {
            s16x8 af[2], bf[2];
#pragma unroll
            for (int mi = 0; mi < 2; ++mi) {
                const int row = wm + mi * 16 + l15;
                const int chunk = (ks * 4 + l4) ^ (row & 7);
                af[mi] = *(const s16x8*)(As + row * 128 + chunk * 16);
            }
#pragma unroll
            for (int ni = 0; ni < 2; ++ni) {
                const int row = wn + ni * 16 + l15;
                const int chunk = (ks * 4 + l4) ^ (row & 7);
                bf[ni] = *(const s16x8*)(Bs + row * 128 + chunk * 16);
            }
#pragma unroll
            for (int mi = 0; mi < 2; ++mi)
#pragma unroll
                for (int ni = 0; ni < 2; ++ni)
                    acc[mi][ni] = __builtin_amdgcn_mfma_f32_16x16x32_bf16(
                        af[mi], bf[ni], acc[mi][ni], 0, 0, 0);
        }
    }

#pragma unroll
    for (int mi = 0; mi < 2; ++mi)
#pragma unroll
        for (int ni = 0; ni < 2; ++ni) {
            const int gm0 = bm + wm + mi * 16 + l4 * 4;
            const int gn  = bn + wn + ni * 16 + l15;
            const float badd = (gn < H_) ? bias[gn] : 0.0f;
#pragma unroll
            for (int r = 0; r < 4; ++r)
                T[(size_t)(gm0 + r) * N_ + gn] = acc[mi][ni][r] + badd;
        }
}

// ---------------------------------------------------------------------------
// Fallback GEMM (R4-style, fp32 inputs) if ws too small for bf16 scratch.
// ---------------------------------------------------------------------------
__global__ __launch_bounds__(256) void gemm_uv_mfma(
        const float* __restrict__ A, const float* __restrict__ W,
        const float* __restrict__ bias, float* __restrict__ T) {
    __shared__ __align__(16) char As[64 * 128];
    __shared__ __align__(16) char Bs[64 * 128];

    const int tid = threadIdx.x;
    const int bm = blockIdx.x * 64;
    const int bn = blockIdx.y * 64;
    const int lane = tid & 63;
    const int wave = tid >> 6;

    const int sr = tid >> 4;
    const int sk = (tid & 15) * 4;
    const float* wbase = (bn < H_) ? (W + (size_t)bn * N_)
                                   : (W + (size_t)(bn - H_) * N_ + H_);

    const int wm = (wave & 1) * 32;
    const int wn = (wave >> 1) * 32;
    const int l15 = lane & 15;
    const int l4  = lane >> 4;

    f32x4 acc[2][2] = {};

    for (int kt = 0; kt < K_; kt += 64) {
        __syncthreads();
#pragma unroll
        for (int ph = 0; ph < 4; ++ph) {
            const int row = ph * 16 + sr;
            const float4 av = *(const float4*)(A + (size_t)(bm + row) * K_ + kt + sk);
            const float4 bv = *(const float4*)(wbase + (size_t)row * N_ + kt + sk);
            const int chunk = sk >> 3;
            const int sub   = (sk & 4) ? 8 : 0;
            const int boff  = row * 128 + ((chunk ^ (row & 7)) * 16) + sub;
            *(uint2*)(As + boff) = make_uint2(pack_bf16(av.x, av.y), pack_bf16(av.z, av.w));
            *(uint2*)(Bs + boff) = make_uint2(pack_bf16(bv.x, bv.y), pack_bf16(bv.z, bv.w));
        }
        __syncthreads();
#pragma unroll
        for (int ks = 0; ks < 2; ++ks) {
            s16x8 af[2], bf[2];
#pragma unroll
            for (int mi = 0; mi < 2; ++mi) {
                const int row = wm + mi * 16 + l15;
                const int chunk = (ks * 4 + l4) ^ (row & 7);
                af[mi] = *(const s16x8*)(As + row * 128 + chunk * 16);
            }
#pragma unroll
            for (int ni = 0; ni < 2; ++ni) {
                const int row = wn + ni * 16 + l15;
                const int chunk = (ks * 4 + l4) ^ (row & 7);
                bf[ni] = *(const s16x8*)(Bs + row * 128 + chunk * 16);
            }
#pragma unroll
            for (int mi = 0; mi < 2; ++mi)
#pragma unroll
                for (int ni = 0; ni < 2; ++ni)
                    acc[mi][ni] = __builtin_amdgcn_mfma_f32_16x16x32_bf16(
                        af[mi], bf[ni], acc[mi][ni], 0, 0, 0);
        }
    }

#pragma unroll
    for (int mi = 0; mi < 2; ++mi)
#pragma unroll
        for (int ni = 0; ni < 2; ++ni) {
            const int gm0 = bm + wm + mi * 16 + l4 * 4;
            const int gn  = bn + wn + ni * 16 + l15;
            const float badd = (gn < H_) ? bias[gn] : 0.0f;
#pragma unroll
            for (int r = 0; r < 4; ++r)
                T[(size_t)(gm0 + r) * N_ + gn] = acc[mi][ni][r] + badd;
        }
}

// tanh(x) = 1 - 2/(exp2(2*log2e*x)+1); exact at +-inf. 5 VALU ops.
__device__ __forceinline__ float fast_tanh(float x) {
    const float e = __builtin_amdgcn_exp2f(x * 2.885390081777926815f);
    const float r = __builtin_amdgcn_rcpf(e + 1.0f);
    return fmaf(-2.0f, r, 1.0f);
}

__device__ __forceinline__ f32x4 tanh4(f32x4 u, f32x4 v) {
    f32x4 o;
    o.x = fast_tanh(u.x + v.x);
    o.y = fast_tanh(u.y + v.y);
    o.z = fast_tanh(u.z + v.z);
    o.w = fast_tanh(u.w + v.w);
    return o;
}

// ---------------------------------------------------------------------------
// Epilogue v3 "dense front": grid-stride over output ROWS in LINEAR order,
// exactly like fillBuffer's write pattern (adjacent blocks write adjacent
// 3KB rows at the same moment -> one dense moving write front, minimal open
// DRAM rows), instead of 2048 independent streams. Per row r: b = r/P,
// p = r%P, invert p -> i via exact closed form (263169-8p = (513-2i)^2 at
// row starts, so fp32 sqrt + +-1 fixup is exact), j = p - off(i) + i.
// U/V slices are L2-resident reads (~808 MB @ ~34 TB/s, hidden); NT store.
// off(i) = i*(513-i)/2.
// ---------------------------------------------------------------------------
#define NROWS_ (B_ * P_)   // 131584

__global__ __launch_bounds__(192) void handshake_epilogue_front(
        const float* __restrict__ T,
        float* __restrict__ out) {
    const int h = threadIdx.x * 4;      // 192 threads * 4 = 768 floats/row
    const int stride = gridDim.x;

    for (int r = blockIdx.x; r < NROWS_; r += stride) {
        const int b = r / P_;            // 0..3 (magic-mul)
        const int p = r - b * P_;        // 0..P-1

        // Invert p -> i:  i = floor((513 - sqrt(263169 - 8p)) / 2), fixups.
        const float Df = (float)(263169 - 8 * p);   // exact in fp32 (< 2^24)
        int i = (int)((513.0f - __builtin_sqrtf(Df)) * 0.5f);
        if ((i + 1) * (513 - (i + 1)) / 2 <= p) ++i;   // sqrt rounded up
        if (i * (513 - i) / 2 > p) --i;                // sqrt rounded down
        const int j = p - i * (513 - i) / 2 + i;       // i <= j < 256

        const float* Tb = T + (size_t)b * L_ * N_;
        const f32x4 u = *(const f32x4*)(Tb + (size_t)i * N_ + h);
        const f32x4 v = *(const f32x4*)(Tb + (size_t)j * N_ + H_ + h);
        __builtin_nontemporal_store(tanh4(u, v),
                                    (f32x4*)(out + (size_t)r * H_ + h));
    }
}

extern "C" void kernel_launch(void* const* d_in, const int* in_sizes, int n_in,
                              void* d_out, int out_size, void* d_ws, size_t ws_size,
                              hipStream_t stream) {
    const float* seq  = (const float*)d_in[0];   // (B, L, H) fp32
    const float* W    = (const float*)d_in[1];   // (H, 2H) fp32
    const float* bias = (const float*)d_in[2];   // (H,) fp32
    float* out = (float*)d_out;                  // (B, P, H) fp32

    char* ws = (char*)d_ws;
    float* T = (float*)ws;                               // 6.29 MB
    const size_t T_BYTES = (size_t)M_ * N_ * 4;
    unsigned short* Abf = (unsigned short*)(ws + T_BYTES);               // 1.57 MB
    unsigned short* Wbf = (unsigned short*)(ws + T_BYTES + (size_t)M_ * K_ * 2); // 2.36 MB
    const size_t NEED = T_BYTES + (size_t)M_ * K_ * 2 + (size_t)K_ * N_ * 2;

    dim3 g1(M_ / 64, N_ / 64);                   // 16 x 24 = 384 blocks
    if (ws_size >= NEED) {
        convert_to_bf16<<<1920, 256, 0, stream>>>(seq, W, Abf, Wbf);
        gemm_uv_bf16<<<g1, 256, 0, stream>>>(Abf, Wbf, bias, T);
    } else {
        gemm_uv_mfma<<<g1, 256, 0, stream>>>(seq, W, bias, T);
    }

    handshake_epilogue_front<<<2048, 192, 0, stream>>>(T, out);
}

// Round 14
// 93.941 us; speedup vs baseline: 2.1933x; 1.0060x over previous
//
#include <hip/hip_runtime.h>
#include <hip/hip_bf16.h>
#include <math.h>

// Shapes (fixed by reference)
#define B_ 4
#define L_ 256
#define H_ 768
#define P_ 32896   // L*(L+1)/2
#define N_ 1536    // 2*H
#define K_ 768
#define M_ 1024    // B*L

typedef __attribute__((ext_vector_type(4))) float f32x4;
typedef __attribute__((ext_vector_type(8))) short s16x8;
typedef const __attribute__((address_space(1))) void* gptr_t;
typedef __attribute__((address_space(3))) void* sptr_t;

__device__ __forceinline__ unsigned pack_bf16(float x, float y) {
    __hip_bfloat16 hx = __float2bfloat16(x);   // RTN
    __hip_bfloat16 hy = __float2bfloat16(y);
    const unsigned short ux = *(const unsigned short*)&hx;
    const unsigned short uy = *(const unsigned short*)&hy;
    return (unsigned)ux | ((unsigned)uy << 16);
}

// ---------------------------------------------------------------------------
// Stage 0: fp32 -> bf16 conversion (memory-bound, ~29 MB traffic, ~5 us).
// ---------------------------------------------------------------------------
__global__ __launch_bounds__(256) void convert_to_bf16(
        const float* __restrict__ A, const float* __restrict__ W,
        unsigned short* __restrict__ Abf, unsigned short* __restrict__ Wbf) {
    const int idx = blockIdx.x * 256 + threadIdx.x;   // float4 index
    const int nA4 = (M_ * K_) / 4;                    // 196608
    const int nW4 = (H_ * N_) / 4;                    // 294912
    if (idx < nA4) {
        const float4 v = ((const float4*)A)[idx];
        ((uint2*)Abf)[idx] = make_uint2(pack_bf16(v.x, v.y), pack_bf16(v.z, v.w));
    } else if (idx < nA4 + nW4) {
        const int wi = idx - nA4;
        const int h  = wi / 384;          // 384 float4 per W row
        const int c  = (wi % 384) * 4;
        const float4 v = ((const float4*)W)[wi];
        const int n = h + ((c >= 768) ? 768 : 0);
        const int k = (c >= 768) ? (c - 768) : c;
        *(uint2*)(Wbf + (size_t)n * K_ + k) =
            make_uint2(pack_bf16(v.x, v.y), pack_bf16(v.z, v.w));
    }
}

// ---------------------------------------------------------------------------
// Stage 1: bf16 MFMA GEMM, DOUBLE-BUFFERED global_load_lds staging.
// R13 structure exposed ~300cy of staging latency per K-step (STAGE between
// two barriers, zero overlap). Now: stage tile t+1 into buf[cur^1] BEFORE
// computing tile t from buf[cur]; single barrier per step (end-of-iteration
// barrier both completes the in-flight loads and guards WAR for t+2's stage).
// LDS 2 x (8KB A + 8KB B) = 32 KB.
// ---------------------------------------------------------------------------
__global__ __launch_bounds__(256) void gemm_uv_bf16(
        const unsigned short* __restrict__ Abf,
        const unsigned short* __restrict__ Wbf,
        const float* __restrict__ bias, float* __restrict__ T) {
    __shared__ __align__(16) char As[2][64 * 128];
    __shared__ __align__(16) char Bs[2][64 * 128];

    const int tid  = threadIdx.x;
    const int bm   = blockIdx.x * 64;
    const int bn   = blockIdx.y * 64;
    const int lane = tid & 63;
    const int wave = tid >> 6;

    const int wm  = (wave & 1) * 32;
    const int wn  = (wave >> 1) * 32;
    const int l15 = lane & 15;
    const int l4  = lane >> 4;

    const int rl = lane >> 3;            // row within 8-row issue
    const int cc = lane & 7;             // 16B chunk within row
    const int srow0 = wave * 16;         // this wave's staging row base
    const int r0 = srow0 + rl;           // issue 0 row
    const int r1 = srow0 + 8 + rl;       // issue 1 row
    const int cp0 = cc ^ (r0 & 7);       // pre-swizzled source chunks
    const int cp1 = cc ^ (r1 & 7);
    const unsigned short* a0p = Abf + (size_t)(bm + r0) * K_ + cp0 * 8;
    const unsigned short* a1p = Abf + (size_t)(bm + r1) * K_ + cp1 * 8;
    const unsigned short* w0p = Wbf + (size_t)(bn + r0) * K_ + cp0 * 8;
    const unsigned short* w1p = Wbf + (size_t)(bn + r1) * K_ + cp1 * 8;

    f32x4 acc[2][2] = {};

#define STAGE(bb, kt)                                                        \
    do {                                                                     \
        __builtin_amdgcn_global_load_lds((gptr_t)(a0p + (kt)),               \
            (sptr_t)(As[bb] + srow0 * 128), 16, 0, 0);                       \
        __builtin_amdgcn_global_load_lds((gptr_t)(w0p + (kt)),               \
            (sptr_t)(Bs[bb] + srow0 * 128), 16, 0, 0);                       \
        __builtin_amdgcn_global_load_lds((gptr_t)(a1p + (kt)),               \
            (sptr_t)(As[bb] + (srow0 + 8) * 128), 16, 0, 0);                 \
        __builtin_amdgcn_global_load_lds((gptr_t)(w1p + (kt)),               \
            (sptr_t)(Bs[bb] + (srow0 + 8) * 128), 16, 0, 0);                 \
    } while (0)

    STAGE(0, 0);
    __syncthreads();

    for (int t = 0; t < 12; ++t) {
        const int cur = t & 1;
        if (t + 1 < 12) STAGE(cur ^ 1, (t + 1) * 64);   // early issue

        const char* pA = As[cur];
        const char* pB = Bs[cur];
#pragma unroll
        for (int ks = 0; ks < 2; ++ks) {
            s16x8 af[2], bf[2];
#pragma unroll
            for (int mi = 0; mi < 2; ++mi) {
                const int row = wm + mi * 16 + l15;
                const int chunk = (ks * 4 + l4) ^ (row & 7);
                af[mi] = *(const s16x8*)(pA + row * 128 + chunk * 16);
            }
#pragma unroll
            for (int ni = 0; ni < 2; ++ni) {
                const int row = wn + ni * 16 + l15;
                const int chunk = (ks * 4 + l4) ^ (row & 7);
                bf[ni] = *(const s16x8*)(pB + row * 128 + chunk * 16);
            }
#pragma unroll
            for (int mi = 0; mi < 2; ++mi)
#pragma unroll
                for (int ni = 0; ni < 2; ++ni)
                    acc[mi][ni] = __builtin_amdgcn_mfma_f32_16x16x32_bf16(
                        af[mi], bf[ni], acc[mi][ni], 0, 0, 0);
        }
        __syncthreads();   // completes in-flight loads; WAR guard for cur
    }
#undef STAGE

#pragma unroll
    for (int mi = 0; mi < 2; ++mi)
#pragma unroll
        for (int ni = 0; ni < 2; ++ni) {
            const int gm0 = bm + wm + mi * 16 + l4 * 4;
            const int gn  = bn + wn + ni * 16 + l15;
            const float badd = (gn < H_) ? bias[gn] : 0.0f;
#pragma unroll
            for (int r = 0; r < 4; ++r)
                T[(size_t)(gm0 + r) * N_ + gn] = acc[mi][ni][r] + badd;
        }
}

// ---------------------------------------------------------------------------
// Fallback GEMM (R4-style, fp32 inputs) if ws too small for bf16 scratch.
// ---------------------------------------------------------------------------
__global__ __launch_bounds__(256) void gemm_uv_mfma(
        const float* __restrict__ A, const float* __restrict__ W,
        const float* __restrict__ bias, float* __restrict__ T) {
    __shared__ __align__(16) char As[64 * 128];
    __shared__ __align__(16) char Bs[64 * 128];

    const int tid = threadIdx.x;
    const int bm = blockIdx.x * 64;
    const int bn = blockIdx.y * 64;
    const int lane = tid & 63;
    const int wave = tid >> 6;

    const int sr = tid >> 4;
    const int sk = (tid & 15) * 4;
    const float* wbase = (bn < H_) ? (W + (size_t)bn * N_)
                                   : (W + (size_t)(bn - H_) * N_ + H_);

    const int wm = (wave & 1) * 32;
    const int wn = (wave >> 1) * 32;
    const int l15 = lane & 15;
    const int l4  = lane >> 4;

    f32x4 acc[2][2] = {};

    for (int kt = 0; kt < K_; kt += 64) {
        __syncthreads();
#pragma unroll
        for (int ph = 0; ph < 4; ++ph) {
            const int row = ph * 16 + sr;
            const float4 av = *(const float4*)(A + (size_t)(bm + row) * K_ + kt + sk);
            const float4 bv = *(const float4*)(wbase + (size_t)row * N_ + kt + sk);
            const int chunk = sk >> 3;
            const int sub   = (sk & 4) ? 8 : 0;
            const int boff  = row * 128 + ((chunk ^ (row & 7)) * 16) + sub;
            *(uint2*)(As + boff) = make_uint2(pack_bf16(av.x, av.y), pack_bf16(av.z, av.w));
            *(uint2*)(Bs + boff) = make_uint2(pack_bf16(bv.x, bv.y), pack_bf16(bv.z, bv.w));
        }
        __syncthreads();
#pragma unroll
        for (int ks = 0; ks < 2; ++ks) {
            s16x8 af[2], bf[2];
#pragma unroll
            for (int mi = 0; mi < 2; ++mi) {
                const int row = wm + mi * 16 + l15;
                const int chunk = (ks * 4 + l4) ^ (row & 7);
                af[mi] = *(const s16x8*)(As + row * 128 + chunk * 16);
            }
#pragma unroll
            for (int ni = 0; ni < 2; ++ni) {
                const int row = wn + ni * 16 + l15;
                const int chunk = (ks * 4 + l4) ^ (row & 7);
                bf[ni] = *(const s16x8*)(Bs + row * 128 + chunk * 16);
            }
#pragma unroll
            for (int mi = 0; mi < 2; ++mi)
#pragma unroll
                for (int ni = 0; ni < 2; ++ni)
                    acc[mi][ni] = __builtin_amdgcn_mfma_f32_16x16x32_bf16(
                        af[mi], bf[ni], acc[mi][ni], 0, 0, 0);
        }
    }

#pragma unroll
    for (int mi = 0; mi < 2; ++mi)
#pragma unroll
        for (int ni = 0; ni < 2; ++ni) {
            const int gm0 = bm + wm + mi * 16 + l4 * 4;
            const int gn  = bn + wn + ni * 16 + l15;
            const float badd = (gn < H_) ? bias[gn] : 0.0f;
#pragma unroll
            for (int r = 0; r < 4; ++r)
                T[(size_t)(gm0 + r) * N_ + gn] = acc[mi][ni][r] + badd;
        }
}

// tanh(x) = 1 - 2/(exp2(2*log2e*x)+1); exact at +-inf. 5 VALU ops.
__device__ __forceinline__ float fast_tanh(float x) {
    const float e = __builtin_amdgcn_exp2f(x * 2.885390081777926815f);
    const float r = __builtin_amdgcn_rcpf(e + 1.0f);
    return fmaf(-2.0f, r, 1.0f);
}

__device__ __forceinline__ f32x4 tanh4(f32x4 u, f32x4 v) {
    f32x4 o;
    o.x = fast_tanh(u.x + v.x);
    o.y = fast_tanh(u.y + v.y);
    o.z = fast_tanh(u.z + v.z);
    o.w = fast_tanh(u.w + v.w);
    return o;
}

// ---------------------------------------------------------------------------
// Epilogue v4 = R13's dense-front + LDS (b,i,j) table. The p->(i,j) sqrt
// inversion (~25 VALU/iter, redundantly computed by all 192 threads) is
// hoisted: the block's <=65 grid-stride rows are inverted in parallel (one
// thread each) into LDS; the hot loop is pure load -> tanh -> NT store.
// ---------------------------------------------------------------------------
#define NROWS_ (B_ * P_)   // 131584
#define EGRID_ 2048

__global__ __launch_bounds__(192) void handshake_epilogue_front(
        const float* __restrict__ T,
        float* __restrict__ out) {
    __shared__ uint2 ij[72];            // (b<<16|i, j) per row-iteration
    const int h = threadIdx.x * 4;      // 192 threads * 4 = 768 floats/row
    const int r0 = blockIdx.x;
    const int cnt = 1 + (NROWS_ - 1 - r0) / EGRID_;   // 64 or 65

    if (threadIdx.x < cnt) {
        const int r = r0 + (int)threadIdx.x * EGRID_;
        const int b = r / P_;
        const int p = r - b * P_;
        // i = floor((513 - sqrt(263169 - 8p))/2), exact fixups.
        const float Df = (float)(263169 - 8 * p);
        int i = (int)((513.0f - __builtin_sqrtf(Df)) * 0.5f);
        if ((i + 1) * (513 - (i + 1)) / 2 <= p) ++i;
        if (i * (513 - i) / 2 > p) --i;
        const int j = p - i * (513 - i) / 2 + i;
        ij[threadIdx.x] = make_uint2((unsigned)((b << 16) | i), (unsigned)j);
    }
    __syncthreads();

    for (int k = 0; k < cnt; ++k) {
        const uint2 e = ij[k];
        const int b = (int)(e.x >> 16);
        const int i = (int)(e.x & 0xffff);
        const int j = (int)e.y;
        const int r = r0 + k * EGRID_;

        const float* Tb = T + (size_t)b * L_ * N_;
        const f32x4 u = *(const f32x4*)(Tb + (size_t)i * N_ + h);
        const f32x4 v = *(const f32x4*)(Tb + (size_t)j * N_ + H_ + h);
        __builtin_nontemporal_store(tanh4(u, v),
                                    (f32x4*)(out + (size_t)r * H_ + h));
    }
}

extern "C" void kernel_launch(void* const* d_in, const int* in_sizes, int n_in,
                              void* d_out, int out_size, void* d_ws, size_t ws_size,
                              hipStream_t stream) {
    const float* seq  = (const float*)d_in[0];   // (B, L, H) fp32
    const float* W    = (const float*)d_in[1];   // (H, 2H) fp32
    const float* bias = (const float*)d_in[2];   // (H,) fp32
    float* out = (float*)d_out;                  // (B, P, H) fp32

    char* ws = (char*)d_ws;
    float* T = (float*)ws;                               // 6.29 MB
    const size_t T_BYTES = (size_t)M_ * N_ * 4;
    unsigned short* Abf = (unsigned short*)(ws + T_BYTES);               // 1.57 MB
    unsigned short* Wbf = (unsigned short*)(ws + T_BYTES + (size_t)M_ * K_ * 2); // 2.36 MB
    const size_t NEED = T_BYTES + (size_t)M_ * K_ * 2 + (size_t)K_ * N_ * 2;

    dim3 g1(M_ / 64, N_ / 64);                   // 16 x 24 = 384 blocks
    if (ws_size >= NEED) {
        convert_to_bf16<<<1920, 256, 0, stream>>>(seq, W, Abf, Wbf);
        gemm_uv_bf16<<<g1, 256, 0, stream>>>(Abf, Wbf, bias, T);
    } else {
        gemm_uv_mfma<<<g1, 256, 0, stream>>>(seq, W, bias, T);
    }

    handshake_epilogue_front<<<EGRID_, 192, 0, stream>>>(T, out);
}

// Round 15
// 93.548 us; speedup vs baseline: 2.2025x; 1.0042x over previous
//
#include <hip/hip_runtime.h>
#include <hip/hip_bf16.h>
#include <math.h>

// Shapes (fixed by reference)
#define B_ 4
#define L_ 256
#define H_ 768
#define P_ 32896   // L*(L+1)/2
#define N_ 1536    // 2*H
#define K_ 768
#define M_ 1024    // B*L

typedef __attribute__((ext_vector_type(4))) float f32x4;
typedef __attribute__((ext_vector_type(8))) short s16x8;
typedef const __attribute__((address_space(1))) void* gptr_t;
typedef __attribute__((address_space(3))) void* sptr_t;

__device__ __forceinline__ unsigned pack_bf16(float x, float y) {
    __hip_bfloat16 hx = __float2bfloat16(x);   // RTN
    __hip_bfloat16 hy = __float2bfloat16(y);
    const unsigned short ux = *(const unsigned short*)&hx;
    const unsigned short uy = *(const unsigned short*)&hy;
    return (unsigned)ux | ((unsigned)uy << 16);
}

// ---------------------------------------------------------------------------
// Stage 0: fp32 -> bf16 conversion (memory-bound, ~16 MB traffic).
// ---------------------------------------------------------------------------
__global__ __launch_bounds__(256) void convert_to_bf16(
        const float* __restrict__ A, const float* __restrict__ W,
        unsigned short* __restrict__ Abf, unsigned short* __restrict__ Wbf) {
    const int idx = blockIdx.x * 256 + threadIdx.x;   // float4 index
    const int nA4 = (M_ * K_) / 4;                    // 196608
    const int nW4 = (H_ * N_) / 4;                    // 294912
    if (idx < nA4) {
        const float4 v = ((const float4*)A)[idx];
        ((uint2*)Abf)[idx] = make_uint2(pack_bf16(v.x, v.y), pack_bf16(v.z, v.w));
    } else if (idx < nA4 + nW4) {
        const int wi = idx - nA4;
        const int h  = wi / 384;          // 384 float4 per W row
        const int c  = (wi % 384) * 4;
        const float4 v = ((const float4*)W)[wi];
        const int n = h + ((c >= 768) ? 768 : 0);
        const int k = (c >= 768) ? (c - 768) : c;
        *(uint2*)(Wbf + (size_t)n * K_ + k) =
            make_uint2(pack_bf16(v.x, v.y), pack_bf16(v.z, v.w));
    }
}

// ---------------------------------------------------------------------------
// Stage 1: bf16 MFMA GEMM, double-buffered global_load_lds staging (R14).
// ---------------------------------------------------------------------------
__global__ __launch_bounds__(256) void gemm_uv_bf16(
        const unsigned short* __restrict__ Abf,
        const unsigned short* __restrict__ Wbf,
        const float* __restrict__ bias, float* __restrict__ T) {
    __shared__ __align__(16) char As[2][64 * 128];
    __shared__ __align__(16) char Bs[2][64 * 128];

    const int tid  = threadIdx.x;
    const int bm   = blockIdx.x * 64;
    const int bn   = blockIdx.y * 64;
    const int lane = tid & 63;
    const int wave = tid >> 6;

    const int wm  = (wave & 1) * 32;
    const int wn  = (wave >> 1) * 32;
    const int l15 = lane & 15;
    const int l4  = lane >> 4;

    const int rl = lane >> 3;
    const int cc = lane & 7;
    const int srow0 = wave * 16;
    const int r0 = srow0 + rl;
    const int r1 = srow0 + 8 + rl;
    const int cp0 = cc ^ (r0 & 7);
    const int cp1 = cc ^ (r1 & 7);
    const unsigned short* a0p = Abf + (size_t)(bm + r0) * K_ + cp0 * 8;
    const unsigned short* a1p = Abf + (size_t)(bm + r1) * K_ + cp1 * 8;
    const unsigned short* w0p = Wbf + (size_t)(bn + r0) * K_ + cp0 * 8;
    const unsigned short* w1p = Wbf + (size_t)(bn + r1) * K_ + cp1 * 8;

    f32x4 acc[2][2] = {};

#define STAGE(bb, kt)                                                        \
    do {                                                                     \
        __builtin_amdgcn_global_load_lds((gptr_t)(a0p + (kt)),               \
            (sptr_t)(As[bb] + srow0 * 128), 16, 0, 0);                       \
        __builtin_amdgcn_global_load_lds((gptr_t)(w0p + (kt)),               \
            (sptr_t)(Bs[bb] + srow0 * 128), 16, 0, 0);                       \
        __builtin_amdgcn_global_load_lds((gptr_t)(a1p + (kt)),               \
            (sptr_t)(As[bb] + (srow0 + 8) * 128), 16, 0, 0);                 \
        __builtin_amdgcn_global_load_lds((gptr_t)(w1p + (kt)),               \
            (sptr_t)(Bs[bb] + (srow0 + 8) * 128), 16, 0, 0);                 \
    } while (0)

    STAGE(0, 0);
    __syncthreads();

    for (int t = 0; t < 12; ++t) {
        const int cur = t & 1;
        if (t + 1 < 12) STAGE(cur ^ 1, (t + 1) * 64);   // early issue

        const char* pA = As[cur];
        const char* pB = Bs[cur];
#pragma unroll
        for (int ks = 0; ks < 2; ++ks) {
            s16x8 af[2], bf[2];
#pragma unroll
            for (int mi = 0; mi < 2; ++mi) {
                const int row = wm + mi * 16 + l15;
                const int chunk = (ks * 4 + l4) ^ (row & 7);
                af[mi] = *(const s16x8*)(pA + row * 128 + chunk * 16);
            }
#pragma unroll
            for (int ni = 0; ni < 2; ++ni) {
                const int row = wn + ni * 16 + l15;
                const int chunk = (ks * 4 + l4) ^ (row & 7);
                bf[ni] = *(const s16x8*)(pB + row * 128 + chunk * 16);
            }
#pragma unroll
            for (int mi = 0; mi < 2; ++mi)
#pragma unroll
                for (int ni = 0; ni < 2; ++ni)
                    acc[mi][ni] = __builtin_amdgcn_mfma_f32_16x16x32_bf16(
                        af[mi], bf[ni], acc[mi][ni], 0, 0, 0);
        }
        __syncthreads();
    }
#undef STAGE

#pragma unroll
    for (int mi = 0; mi < 2; ++mi)
#pragma unroll
        for (int ni = 0; ni < 2; ++ni) {
            const int gm0 = bm + wm + mi * 16 + l4 * 4;
            const int gn  = bn + wn + ni * 16 + l15;
            const float badd = (gn < H_) ? bias[gn] : 0.0f;
#pragma unroll
            for (int r = 0; r < 4; ++r)
                T[(size_t)(gm0 + r) * N_ + gn] = acc[mi][ni][r] + badd;
        }
}

// ---------------------------------------------------------------------------
// Fallback GEMM (fp32 inputs) if ws too small for bf16 scratch.
// ---------------------------------------------------------------------------
__global__ __launch_bounds__(256) void gemm_uv_mfma(
        const float* __restrict__ A, const float* __restrict__ W,
        const float* __restrict__ bias, float* __restrict__ T) {
    __shared__ __align__(16) char As[64 * 128];
    __shared__ __align__(16) char Bs[64 * 128];

    const int tid = threadIdx.x;
    const int bm = blockIdx.x * 64;
    const int bn = blockIdx.y * 64;
    const int lane = tid & 63;
    const int wave = tid >> 6;

    const int sr = tid >> 4;
    const int sk = (tid & 15) * 4;
    const float* wbase = (bn < H_) ? (W + (size_t)bn * N_)
                                   : (W + (size_t)(bn - H_) * N_ + H_);

    const int wm = (wave & 1) * 32;
    const int wn = (wave >> 1) * 32;
    const int l15 = lane & 15;
    const int l4  = lane >> 4;

    f32x4 acc[2][2] = {};

    for (int kt = 0; kt < K_; kt += 64) {
        __syncthreads();
#pragma unroll
        for (int ph = 0; ph < 4; ++ph) {
            const int row = ph * 16 + sr;
            const float4 av = *(const float4*)(A + (size_t)(bm + row) * K_ + kt + sk);
            const float4 bv = *(const float4*)(wbase + (size_t)row * N_ + kt + sk);
            const int chunk = sk >> 3;
            const int sub   = (sk & 4) ? 8 : 0;
            const int boff  = row * 128 + ((chunk ^ (row & 7)) * 16) + sub;
            *(uint2*)(As + boff) = make_uint2(pack_bf16(av.x, av.y), pack_bf16(av.z, av.w));
            *(uint2*)(Bs + boff) = make_uint2(pack_bf16(bv.x, bv.y), pack_bf16(bv.z, bv.w));
        }
        __syncthreads();
#pragma unroll
        for (int ks = 0; ks < 2; ++ks) {
            s16x8 af[2], bf[2];
#pragma unroll
            for (int mi = 0; mi < 2; ++mi) {
                const int row = wm + mi * 16 + l15;
                const int chunk = (ks * 4 + l4) ^ (row & 7);
                af[mi] = *(const s16x8*)(As + row * 128 + chunk * 16);
            }
#pragma unroll
            for (int ni = 0; ni < 2; ++ni) {
                const int row = wn + ni * 16 + l15;
                const int chunk = (ks * 4 + l4) ^ (row & 7);
                bf[ni] = *(const s16x8*)(Bs + row * 128 + chunk * 16);
            }
#pragma unroll
            for (int mi = 0; mi < 2; ++mi)
#pragma unroll
                for (int ni = 0; ni < 2; ++ni)
                    acc[mi][ni] = __builtin_amdgcn_mfma_f32_16x16x32_bf16(
                        af[mi], bf[ni], acc[mi][ni], 0, 0, 0);
        }
    }

#pragma unroll
    for (int mi = 0; mi < 2; ++mi)
#pragma unroll
        for (int ni = 0; ni < 2; ++ni) {
            const int gm0 = bm + wm + mi * 16 + l4 * 4;
            const int gn  = bn + wn + ni * 16 + l15;
            const float badd = (gn < H_) ? bias[gn] : 0.0f;
#pragma unroll
            for (int r = 0; r < 4; ++r)
                T[(size_t)(gm0 + r) * N_ + gn] = acc[mi][ni][r] + badd;
        }
}

// tanh(x) = 1 - 2/(exp2(2*log2e*x)+1); exact at +-inf. 5 VALU ops.
__device__ __forceinline__ float fast_tanh(float x) {
    const float e = __builtin_amdgcn_exp2f(x * 2.885390081777926815f);
    const float r = __builtin_amdgcn_rcpf(e + 1.0f);
    return fmaf(-2.0f, r, 1.0f);
}

__device__ __forceinline__ f32x4 tanh4(f32x4 u, f32x4 v) {
    f32x4 o;
    o.x = fast_tanh(u.x + v.x);
    o.y = fast_tanh(u.y + v.y);
    o.z = fast_tanh(u.z + v.z);
    o.w = fast_tanh(u.w + v.w);
    return o;
}

// ---------------------------------------------------------------------------
// Epilogue v5 "quad dense front": grid-stride over QUADS of 4 consecutive
// output rows (4 | P so a quad never straddles a batch). One sqrt inversion
// per quad, then incremental (i,j) advance (++j; rollover j==256 -> ++i,j=i).
// U row register-cached across the quad (reload only on rollover); V rows
// j..j+3 form a 12KB sequential read; block writes 12KB contiguous per iter.
// vs R13: reads 790 -> ~525 MB, read/write streams both more sequential,
// write front stays dense (1024 blocks x 12KB).
// ---------------------------------------------------------------------------
#define NROWS_ (B_ * P_)    // 131584
#define NQUAD_ (NROWS_ / 4) // 32896
#define EGRID_ 1024

__global__ __launch_bounds__(192) void handshake_epilogue_quad(
        const float* __restrict__ T,
        float* __restrict__ out) {
    const int h = threadIdx.x * 4;      // 192 threads * 4 = 768 floats/row

    for (int q = blockIdx.x; q < NQUAD_; q += EGRID_) {
        const int rbase = q * 4;
        const int b  = rbase / P_;       // same b for all 4 rows (4 | P_)
        const int p0 = rbase - b * P_;

        // Invert p0 -> i: i = floor((513 - sqrt(263169 - 8p))/2), fixups.
        const float Df = (float)(263169 - 8 * p0);   // exact in fp32
        int i = (int)((513.0f - __builtin_sqrtf(Df)) * 0.5f);
        if ((i + 1) * (513 - (i + 1)) / 2 <= p0) ++i;
        if (i * (513 - i) / 2 > p0) --i;
        int j = p0 - i * (513 - i) / 2 + i;          // i <= j < 256

        const float* Tb = T + (size_t)b * L_ * N_;
        f32x4 u = *(const f32x4*)(Tb + (size_t)i * N_ + h);
        float* orow = out + (size_t)rbase * H_ + h;

#pragma unroll
        for (int k = 0; k < 4; ++k) {
            const f32x4 v = *(const f32x4*)(Tb + (size_t)j * N_ + H_ + h);
            __builtin_nontemporal_store(tanh4(u, v), (f32x4*)orow);
            orow += H_;
            // advance to next row's (i,j); reload u only on rollover
            ++j;
            if (j == 256) {              // block-uniform branch
                ++i; j = i;
                u = *(const f32x4*)(Tb + (size_t)i * N_ + h);
            }
        }
    }
}

extern "C" void kernel_launch(void* const* d_in, const int* in_sizes, int n_in,
                              void* d_out, int out_size, void* d_ws, size_t ws_size,
                              hipStream_t stream) {
    const float* seq  = (const float*)d_in[0];   // (B, L, H) fp32
    const float* W    = (const float*)d_in[1];   // (H, 2H) fp32
    const float* bias = (const float*)d_in[2];   // (H,) fp32
    float* out = (float*)d_out;                  // (B, P, H) fp32

    char* ws = (char*)d_ws;
    float* T = (float*)ws;                               // 6.29 MB
    const size_t T_BYTES = (size_t)M_ * N_ * 4;
    unsigned short* Abf = (unsigned short*)(ws + T_BYTES);               // 1.57 MB
    unsigned short* Wbf = (unsigned short*)(ws + T_BYTES + (size_t)M_ * K_ * 2); // 2.36 MB
    const size_t NEED = T_BYTES + (size_t)M_ * K_ * 2 + (size_t)K_ * N_ * 2;

    dim3 g1(M_ / 64, N_ / 64);                   // 16 x 24 = 384 blocks
    if (ws_size >= NEED) {
        convert_to_bf16<<<1920, 256, 0, stream>>>(seq, W, Abf, Wbf);
        gemm_uv_bf16<<<g1, 256, 0, stream>>>(Abf, Wbf, bias, T);
    } else {
        gemm_uv_mfma<<<g1, 256, 0, stream>>>(seq, W, bias, T);
    }

    handshake_epilogue_quad<<<EGRID_, 192, 0, stream>>>(T, out);
}

// Round 16
// 90.873 us; speedup vs baseline: 2.2673x; 1.0294x over previous
//
#include <hip/hip_runtime.h>
#include <hip/hip_bf16.h>
#include <math.h>

// Shapes (fixed by reference)
#define B_ 4
#define L_ 256
#define H_ 768
#define P_ 32896   // L*(L+1)/2
#define N_ 1536    // 2*H
#define K_ 768
#define M_ 1024    // B*L

typedef __attribute__((ext_vector_type(4))) float f32x4;
typedef __attribute__((ext_vector_type(8))) short s16x8;
typedef const __attribute__((address_space(1))) void* gptr_t;
typedef __attribute__((address_space(3))) void* sptr_t;

__device__ __forceinline__ unsigned pack_bf16(float x, float y) {
    __hip_bfloat16 hx = __float2bfloat16(x);   // RTN
    __hip_bfloat16 hy = __float2bfloat16(y);
    const unsigned short ux = *(const unsigned short*)&hx;
    const unsigned short uy = *(const unsigned short*)&hy;
    return (unsigned)ux | ((unsigned)uy << 16);
}

// ---------------------------------------------------------------------------
// Stage 0: fp32 -> bf16 conversion (memory-bound, ~12 MB traffic).
// ---------------------------------------------------------------------------
__global__ __launch_bounds__(256) void convert_to_bf16(
        const float* __restrict__ A, const float* __restrict__ W,
        unsigned short* __restrict__ Abf, unsigned short* __restrict__ Wbf) {
    const int idx = blockIdx.x * 256 + threadIdx.x;   // float4 index
    const int nA4 = (M_ * K_) / 4;                    // 196608
    const int nW4 = (H_ * N_) / 4;                    // 294912
    if (idx < nA4) {
        const float4 v = ((const float4*)A)[idx];
        ((uint2*)Abf)[idx] = make_uint2(pack_bf16(v.x, v.y), pack_bf16(v.z, v.w));
    } else if (idx < nA4 + nW4) {
        const int wi = idx - nA4;
        const int h  = wi / 384;          // 384 float4 per W row
        const int c  = (wi % 384) * 4;
        const float4 v = ((const float4*)W)[wi];
        const int n = h + ((c >= 768) ? 768 : 0);
        const int k = (c >= 768) ? (c - 768) : c;
        *(uint2*)(Wbf + (size_t)n * K_ + k) =
            make_uint2(pack_bf16(v.x, v.y), pack_bf16(v.z, v.w));
    }
}

// ---------------------------------------------------------------------------
// Stage 1: bf16 MFMA GEMM, double-buffered global_load_lds staging, with
// K-SPLIT via blockIdx.z: block (x,y,kz) computes K in [kz*K/Z, (kz+1)*K/Z)
// into partial T + kz*M*N. The GEMM is latency-bound (0.3 us of MFMA in a
// 12-step serial barrier chain at 1.5 blocks/CU); Z=2 halves the serial
// steps and doubles TLP (768 blocks = 3/CU). Bias folded into kz==0 partial.
// ---------------------------------------------------------------------------
__global__ __launch_bounds__(256) void gemm_uv_bf16(
        const unsigned short* __restrict__ Abf,
        const unsigned short* __restrict__ Wbf,
        const float* __restrict__ bias, float* __restrict__ T) {
    __shared__ __align__(16) char As[2][64 * 128];
    __shared__ __align__(16) char Bs[2][64 * 128];

    const int tid  = threadIdx.x;
    const int bm   = blockIdx.x * 64;
    const int bn   = blockIdx.y * 64;
    const int kz   = blockIdx.z;
    const int nst  = 12 / gridDim.z;     // K-steps per block (12 or 6)
    const int koff = kz * nst * 64;
    float* Tout = T + (size_t)kz * M_ * N_;

    const int lane = tid & 63;
    const int wave = tid >> 6;
    const int wm  = (wave & 1) * 32;
    const int wn  = (wave >> 1) * 32;
    const int l15 = lane & 15;
    const int l4  = lane >> 4;

    const int rl = lane >> 3;
    const int cc = lane & 7;
    const int srow0 = wave * 16;
    const int r0 = srow0 + rl;
    const int r1 = srow0 + 8 + rl;
    const int cp0 = cc ^ (r0 & 7);
    const int cp1 = cc ^ (r1 & 7);
    const unsigned short* a0p = Abf + (size_t)(bm + r0) * K_ + koff + cp0 * 8;
    const unsigned short* a1p = Abf + (size_t)(bm + r1) * K_ + koff + cp1 * 8;
    const unsigned short* w0p = Wbf + (size_t)(bn + r0) * K_ + koff + cp0 * 8;
    const unsigned short* w1p = Wbf + (size_t)(bn + r1) * K_ + koff + cp1 * 8;

    f32x4 acc[2][2] = {};

#define STAGE(bb, kt)                                                        \
    do {                                                                     \
        __builtin_amdgcn_global_load_lds((gptr_t)(a0p + (kt)),               \
            (sptr_t)(As[bb] + srow0 * 128), 16, 0, 0);                       \
        __builtin_amdgcn_global_load_lds((gptr_t)(w0p + (kt)),               \
            (sptr_t)(Bs[bb] + srow0 * 128), 16, 0, 0);                       \
        __builtin_amdgcn_global_load_lds((gptr_t)(a1p + (kt)),               \
            (sptr_t)(As[bb] + (srow0 + 8) * 128), 16, 0, 0);                 \
        __builtin_amdgcn_global_load_lds((gptr_t)(w1p + (kt)),               \
            (sptr_t)(Bs[bb] + (srow0 + 8) * 128), 16, 0, 0);                 \
    } while (0)

    STAGE(0, 0);
    __syncthreads();

    for (int t = 0; t < nst; ++t) {
        const int cur = t & 1;
        if (t + 1 < nst) STAGE(cur ^ 1, (t + 1) * 64);   // early issue

        const char* pA = As[cur];
        const char* pB = Bs[cur];
#pragma unroll
        for (int ks = 0; ks < 2; ++ks) {
            s16x8 af[2], bf[2];
#pragma unroll
            for (int mi = 0; mi < 2; ++mi) {
                const int row = wm + mi * 16 + l15;
                const int chunk = (ks * 4 + l4) ^ (row & 7);
                af[mi] = *(const s16x8*)(pA + row * 128 + chunk * 16);
            }
#pragma unroll
            for (int ni = 0; ni < 2; ++ni) {
                const int row = wn + ni * 16 + l15;
                const int chunk = (ks * 4 + l4) ^ (row & 7);
                bf[ni] = *(const s16x8*)(pB + row * 128 + chunk * 16);
            }
#pragma unroll
            for (int mi = 0; mi < 2; ++mi)
#pragma unroll
                for (int ni = 0; ni < 2; ++ni)
                    acc[mi][ni] = __builtin_amdgcn_mfma_f32_16x16x32_bf16(
                        af[mi], bf[ni], acc[mi][ni], 0, 0, 0);
        }
        __syncthreads();
    }
#undef STAGE

#pragma unroll
    for (int mi = 0; mi < 2; ++mi)
#pragma unroll
        for (int ni = 0; ni < 2; ++ni) {
            const int gm0 = bm + wm + mi * 16 + l4 * 4;
            const int gn  = bn + wn + ni * 16 + l15;
            const float badd = (kz == 0 && gn < H_) ? bias[gn] : 0.0f;
#pragma unroll
            for (int r = 0; r < 4; ++r)
                Tout[(size_t)(gm0 + r) * N_ + gn] = acc[mi][ni][r] + badd;
        }
}

// ---------------------------------------------------------------------------
// Fallback GEMM (fp32 inputs) if ws too small for bf16 scratch.
// ---------------------------------------------------------------------------
__global__ __launch_bounds__(256) void gemm_uv_mfma(
        const float* __restrict__ A, const float* __restrict__ W,
        const float* __restrict__ bias, float* __restrict__ T) {
    __shared__ __align__(16) char As[64 * 128];
    __shared__ __align__(16) char Bs[64 * 128];

    const int tid = threadIdx.x;
    const int bm = blockIdx.x * 64;
    const int bn = blockIdx.y * 64;
    const int lane = tid & 63;
    const int wave = tid >> 6;

    const int sr = tid >> 4;
    const int sk = (tid & 15) * 4;
    const float* wbase = (bn < H_) ? (W + (size_t)bn * N_)
                                   : (W + (size_t)(bn - H_) * N_ + H_);

    const int wm = (wave & 1) * 32;
    const int wn = (wave >> 1) * 32;
    const int l15 = lane & 15;
    const int l4  = lane >> 4;

    f32x4 acc[2][2] = {};

    for (int kt = 0; kt < K_; kt += 64) {
        __syncthreads();
#pragma unroll
        for (int ph = 0; ph < 4; ++ph) {
            const int row = ph * 16 + sr;
            const float4 av = *(const float4*)(A + (size_t)(bm + row) * K_ + kt + sk);
            const float4 bv = *(const float4*)(wbase + (size_t)row * N_ + kt + sk);
            const int chunk = sk >> 3;
            const int sub   = (sk & 4) ? 8 : 0;
            const int boff  = row * 128 + ((chunk ^ (row & 7)) * 16) + sub;
            *(uint2*)(As + boff) = make_uint2(pack_bf16(av.x, av.y), pack_bf16(av.z, av.w));
            *(uint2*)(Bs + boff) = make_uint2(pack_bf16(bv.x, bv.y), pack_bf16(bv.z, bv.w));
        }
        __syncthreads();
#pragma unroll
        for (int ks = 0; ks < 2; ++ks) {
            s16x8 af[2], bf[2];
#pragma unroll
            for (int mi = 0; mi < 2; ++mi) {
                const int row = wm + mi * 16 + l15;
                const int chunk = (ks * 4 + l4) ^ (row & 7);
                af[mi] = *(const s16x8*)(As + row * 128 + chunk * 16);
            }
#pragma unroll
            for (int ni = 0; ni < 2; ++ni) {
                const int row = wn + ni * 16 + l15;
                const int chunk = (ks * 4 + l4) ^ (row & 7);
                bf[ni] = *(const s16x8*)(Bs + row * 128 + chunk * 16);
            }
#pragma unroll
            for (int mi = 0; mi < 2; ++mi)
#pragma unroll
                for (int ni = 0; ni < 2; ++ni)
                    acc[mi][ni] = __builtin_amdgcn_mfma_f32_16x16x32_bf16(
                        af[mi], bf[ni], acc[mi][ni], 0, 0, 0);
        }
    }

#pragma unroll
    for (int mi = 0; mi < 2; ++mi)
#pragma unroll
        for (int ni = 0; ni < 2; ++ni) {
            const int gm0 = bm + wm + mi * 16 + l4 * 4;
            const int gn  = bn + wn + ni * 16 + l15;
            const float badd = (gn < H_) ? bias[gn] : 0.0f;
#pragma unroll
            for (int r = 0; r < 4; ++r)
                T[(size_t)(gm0 + r) * N_ + gn] = acc[mi][ni][r] + badd;
        }
}

// tanh(x) = 1 - 2/(exp2(2*log2e*x)+1); exact at +-inf. 5 VALU ops.
__device__ __forceinline__ float fast_tanh(float x) {
    const float e = __builtin_amdgcn_exp2f(x * 2.885390081777926815f);
    const float r = __builtin_amdgcn_rcpf(e + 1.0f);
    return fmaf(-2.0f, r, 1.0f);
}

__device__ __forceinline__ f32x4 tanh4(f32x4 u, f32x4 v) {
    f32x4 o;
    o.x = fast_tanh(u.x + v.x);
    o.y = fast_tanh(u.y + v.y);
    o.z = fast_tanh(u.z + v.z);
    o.w = fast_tanh(u.w + v.w);
    return o;
}

// ---------------------------------------------------------------------------
// Epilogue v6 = R15 quad dense front, reading the K-SPLIT partials
// (u = T0[i]+T1[i], v = T0v[j]+T1v[j]). Reads double vs R15 — proven free
// (R12/R15 A/Bs); writes unchanged.
// ---------------------------------------------------------------------------
#define NROWS_ (B_ * P_)    // 131584
#define NQUAD_ (NROWS_ / 4) // 32896
#define EGRID_ 1024

__global__ __launch_bounds__(192) void handshake_epilogue_quad2(
        const float* __restrict__ T,
        float* __restrict__ out) {
    const int h = threadIdx.x * 4;      // 192 threads * 4 = 768 floats/row
    const float* __restrict__ T1 = T + (size_t)M_ * N_;

    for (int q = blockIdx.x; q < NQUAD_; q += EGRID_) {
        const int rbase = q * 4;
        const int b  = rbase / P_;       // same b for all 4 rows (4 | P_)
        const int p0 = rbase - b * P_;

        const float Df = (float)(263169 - 8 * p0);   // exact in fp32
        int i = (int)((513.0f - __builtin_sqrtf(Df)) * 0.5f);
        if ((i + 1) * (513 - (i + 1)) / 2 <= p0) ++i;
        if (i * (513 - i) / 2 > p0) --i;
        int j = p0 - i * (513 - i) / 2 + i;          // i <= j < 256

        const size_t tb = (size_t)b * L_ * N_;
        f32x4 u = *(const f32x4*)(T + tb + (size_t)i * N_ + h)
                + *(const f32x4*)(T1 + tb + (size_t)i * N_ + h);
        float* orow = out + (size_t)rbase * H_ + h;

#pragma unroll
        for (int k = 0; k < 4; ++k) {
            const f32x4 v = *(const f32x4*)(T + tb + (size_t)j * N_ + H_ + h)
                          + *(const f32x4*)(T1 + tb + (size_t)j * N_ + H_ + h);
            __builtin_nontemporal_store(tanh4(u, v), (f32x4*)orow);
            orow += H_;
            ++j;
            if (j == 256) {              // block-uniform branch
                ++i; j = i;
                u = *(const f32x4*)(T + tb + (size_t)i * N_ + h)
                  + *(const f32x4*)(T1 + tb + (size_t)i * N_ + h);
            }
        }
    }
}

// Single-T epilogue (fallback path).
__global__ __launch_bounds__(192) void handshake_epilogue_quad(
        const float* __restrict__ T,
        float* __restrict__ out) {
    const int h = threadIdx.x * 4;

    for (int q = blockIdx.x; q < NQUAD_; q += EGRID_) {
        const int rbase = q * 4;
        const int b  = rbase / P_;
        const int p0 = rbase - b * P_;

        const float Df = (float)(263169 - 8 * p0);
        int i = (int)((513.0f - __builtin_sqrtf(Df)) * 0.5f);
        if ((i + 1) * (513 - (i + 1)) / 2 <= p0) ++i;
        if (i * (513 - i) / 2 > p0) --i;
        int j = p0 - i * (513 - i) / 2 + i;

        const float* Tb = T + (size_t)b * L_ * N_;
        f32x4 u = *(const f32x4*)(Tb + (size_t)i * N_ + h);
        float* orow = out + (size_t)rbase * H_ + h;

#pragma unroll
        for (int k = 0; k < 4; ++k) {
            const f32x4 v = *(const f32x4*)(Tb + (size_t)j * N_ + H_ + h);
            __builtin_nontemporal_store(tanh4(u, v), (f32x4*)orow);
            orow += H_;
            ++j;
            if (j == 256) {
                ++i; j = i;
                u = *(const f32x4*)(Tb + (size_t)i * N_ + h);
            }
        }
    }
}

extern "C" void kernel_launch(void* const* d_in, const int* in_sizes, int n_in,
                              void* d_out, int out_size, void* d_ws, size_t ws_size,
                              hipStream_t stream) {
    const float* seq  = (const float*)d_in[0];   // (B, L, H) fp32
    const float* W    = (const float*)d_in[1];   // (H, 2H) fp32
    const float* bias = (const float*)d_in[2];   // (H,) fp32
    float* out = (float*)d_out;                  // (B, P, H) fp32

    char* ws = (char*)d_ws;
    float* T = (float*)ws;
    const size_t T_BYTES = (size_t)M_ * N_ * 4;              // 6.29 MB
    const size_t AB_BYTES = (size_t)M_ * K_ * 2;             // 1.57 MB
    const size_t WB_BYTES = (size_t)K_ * N_ * 2;             // 2.36 MB
    const size_t NEED2 = 2 * T_BYTES + AB_BYTES + WB_BYTES;  // 16.5 MB
    const size_t NEED1 = T_BYTES + AB_BYTES + WB_BYTES;      // 10.2 MB

    if (ws_size >= NEED2) {
        unsigned short* Abf = (unsigned short*)(ws + 2 * T_BYTES);
        unsigned short* Wbf = (unsigned short*)(ws + 2 * T_BYTES + AB_BYTES);
        convert_to_bf16<<<1920, 256, 0, stream>>>(seq, W, Abf, Wbf);
        dim3 g1(M_ / 64, N_ / 64, 2);            // 768 blocks, K-split 2
        gemm_uv_bf16<<<g1, 256, 0, stream>>>(Abf, Wbf, bias, T);
        handshake_epilogue_quad2<<<EGRID_, 192, 0, stream>>>(T, out);
    } else if (ws_size >= NEED1) {
        unsigned short* Abf = (unsigned short*)(ws + T_BYTES);
        unsigned short* Wbf = (unsigned short*)(ws + T_BYTES + AB_BYTES);
        convert_to_bf16<<<1920, 256, 0, stream>>>(seq, W, Abf, Wbf);
        dim3 g1(M_ / 64, N_ / 64, 1);            // 384 blocks, no split
        gemm_uv_bf16<<<g1, 256, 0, stream>>>(Abf, Wbf, bias, T);
        handshake_epilogue_quad<<<EGRID_, 192, 0, stream>>>(T, out);
    } else {
        dim3 g1(M_ / 64, N_ / 64);
        gemm_uv_mfma<<<g1, 256, 0, stream>>>(seq, W, bias, T);
        handshake_epilogue_quad<<<EGRID_, 192, 0, stream>>>(T, out);
    }
}